// Round 5
// baseline (679.968 us; speedup 1.0000x reference)
//
#include <hip/hip_runtime.h>

#define NN 20480
#define NPTS 81920   // B(4) * N(20480)

__device__ __forceinline__ float redsum16(float v){
    v += __shfl_xor(v, 1); v += __shfl_xor(v, 2);
    v += __shfl_xor(v, 4); v += __shfl_xor(v, 8);
    return v;
}
__device__ __forceinline__ float redmax16(float v){
    v = fmaxf(v, __shfl_xor(v, 1)); v = fmaxf(v, __shfl_xor(v, 2));
    v = fmaxf(v, __shfl_xor(v, 4)); v = fmaxf(v, __shfl_xor(v, 8));
    return v;
}

// Ultra-vanilla fill: diagnostic carrier + deterministic init.
__global__ void k_fill(float* out, float val, int n){
    int i = blockIdx.x * blockDim.x + threadIdx.x;
    int stride = gridDim.x * blockDim.x;
    for (; i < n; i += stride) out[i] = val;
}

// f_pc = relu(g * (m1_W @ feature) + b), stored point-major (B,N,16) f32
__global__ __launch_bounds__(256) void k_feat0(
    const float* __restrict__ featp,
    const float* __restrict__ m1W,
    const float* __restrict__ m1g,
    const float* __restrict__ m1b,
    float* __restrict__ feat0)
{
    int p = blockIdx.x * 256 + threadIdx.x;
    if (p >= NPTS) return;
    int b = p / NN;
    int n = p - b * NN;
    float x[16];
    #pragma unroll
    for (int c = 0; c < 16; c++) x[c] = featp[(b*16 + c)*NN + n];
    float4* dst = (float4*)(feat0 + (size_t)p * 16);
    #pragma unroll
    for (int v = 0; v < 4; v++){
        float4 t; float* tp = (float*)&t;
        #pragma unroll
        for (int u = 0; u < 4; u++){
            int o = 4*v + u;
            float acc = 0.f;
            #pragma unroll
            for (int c = 0; c < 16; c++) acc = fmaf(m1W[o*16 + c], x[c], acc);
            tp[u] = fmaxf(fmaf(m1g[o], acc, m1b[o]), 0.f);
        }
        dst[v] = t;
    }
}

// Stage 1: geometry + lm1 + gather feat0 + f_dis + pool1 + p1m -> feat1 (f32)
__global__ __launch_bounds__(256) void k_stage1(
    const float* __restrict__ xyzp,
    const int* __restrict__ nidx,
    const float* __restrict__ feat0,
    const float* __restrict__ lm1W,
    const float* __restrict__ lm1g,
    const float* __restrict__ lm1b,
    const float* __restrict__ p1fc,
    const float* __restrict__ p1mW,
    const float* __restrict__ p1mg,
    const float* __restrict__ p1mb,
    float* __restrict__ feat1)
{
    const int k = threadIdx.x & 15;
    const int p = (blockIdx.x << 4) + (threadIdx.x >> 4);
    const int b = p / NN;

    const float sx = xyzp[p*3 + 0];
    const float sy = xyzp[p*3 + 1];
    const float sz = xyzp[p*3 + 2];
    const int ii = nidx[(p << 4) + k];
    const int q  = b * NN + ii;
    const float nx = xyzp[q*3 + 0];
    const float ny = xyzp[q*3 + 1];
    const float nz = xyzp[q*3 + 2];

    float rx = sx - nx, ry = sy - ny, rz = sz - nz;
    float r2 = rx*rx + ry*ry;
    float rdis = sqrtf(r2 + rz*rz);
    float ralpha = atan2f(ry, rx);
    float rbeta  = atan2f(rz, sqrtf(r2));
    float gdis = __expf(-rdis);

    float mx = redsum16(nx) * 0.0625f;
    float my = redsum16(ny) * 0.0625f;
    float mz = redsum16(nz) * 0.0625f;
    float dx = sx - mx, dy = sy - my, dz = sz - mz;
    float dalpha = atan2f(dy, dx);
    float dbeta  = atan2f(dz, sqrtf(dx*dx + dy*dy));

    float rep[9] = { ralpha - dalpha, rbeta - dbeta, rdis, sx, sy, sz, nx, ny, nz };
    float lrep[16];
    #pragma unroll
    for (int o = 0; o < 16; o++){
        float acc = 0.f;
        #pragma unroll
        for (int c = 0; c < 9; c++) acc = fmaf(lm1W[o*9 + c], rep[c], acc);
        lrep[o] = fmaxf(fmaf(lm1g[o], acc, lm1b[o]), 0.f);
    }

    float fnb[16];
    float sd = 0.f;
    {
        const float4* an = (const float4*)(feat0 + (size_t)q * 16);
        const float4* as = (const float4*)(feat0 + (size_t)p * 16);
        #pragma unroll
        for (int v = 0; v < 4; v++){
            float4 A = an[v]; float4 S = as[v];
            fnb[4*v+0] = A.x; fnb[4*v+1] = A.y; fnb[4*v+2] = A.z; fnb[4*v+3] = A.w;
            sd += fabsf(S.x-A.x) + fabsf(S.y-A.y) + fabsf(S.z-A.z) + fabsf(S.w-A.w);
        }
    }
    float fdis2 = 2.f * __expf(-sd * 0.0625f);   // LAMDA * f_dis

    float lg[32];
    #pragma unroll
    for (int o = 0; o < 32; o++){
        const float* w = p1fc + o*34;
        float acc = w[0] * gdis;
        acc = fmaf(w[1], fdis2, acc);
        #pragma unroll
        for (int c = 0; c < 16; c++) acc = fmaf(w[2 + c],  fnb[c],  acc);
        #pragma unroll
        for (int c = 0; c < 16; c++) acc = fmaf(w[18 + c], lrep[c], acc);
        lg[o] = acc;
    }
    // softmax over k (16 lanes) + attention-weighted pool
    #pragma unroll
    for (int o = 0; o < 32; o++){
        float m_ = redmax16(lg[o]);
        float e  = __expf(lg[o] - m_);
        float s  = redsum16(e);
        float fsv = (o < 16) ? fnb[o] : lrep[o - 16];
        float num = redsum16(fsv * e);
        lg[o] = num / s;     // f_lc[o], replicated on all 16 lanes
    }
    // p1m: lane k computes output channel k
    float acc = 0.f;
    #pragma unroll
    for (int c = 0; c < 32; c++) acc = fmaf(p1mW[k*32 + c], lg[c], acc);
    feat1[(size_t)(p << 4) + k] = fmaxf(fmaf(p1mg[k], acc, p1mb[k]), 0.f);
}

// Stage 2: recompute geometry, lm1+lm2, pool2, p2m, m2+sc+m3, m4 -> output (f32)
__global__ __launch_bounds__(256) void k_stage2(
    const float* __restrict__ featp,
    const float* __restrict__ xyzp,
    const int* __restrict__ nidx,
    const float* __restrict__ feat1,
    const float* __restrict__ lm1W,
    const float* __restrict__ lm1g,
    const float* __restrict__ lm1b,
    const float* __restrict__ lm2W,
    const float* __restrict__ lm2g,
    const float* __restrict__ lm2b,
    const float* __restrict__ p2fc,
    const float* __restrict__ p2mW,
    const float* __restrict__ p2mg,
    const float* __restrict__ p2mb,
    const float* __restrict__ m2W,
    const float* __restrict__ m2g,
    const float* __restrict__ m2b,
    const float* __restrict__ scW,
    const float* __restrict__ scg,
    const float* __restrict__ scb,
    const float* __restrict__ m3W,
    const float* __restrict__ m3g,
    const float* __restrict__ m3b,
    const float* __restrict__ m4W,
    const float* __restrict__ m4g,
    const float* __restrict__ m4b,
    float* __restrict__ outp)
{
    __shared__ float sPool[16*132];   // h[128]-stage, then out-transpose (aliased)

    const int k  = threadIdx.x & 15;
    const int pt = threadIdx.x >> 4;
    const int p  = (blockIdx.x << 4) + pt;
    const int b  = p / NN;
    const int n  = p - b * NN;

    const float sx = xyzp[p*3 + 0];
    const float sy = xyzp[p*3 + 1];
    const float sz = xyzp[p*3 + 2];
    const int ii = nidx[(p << 4) + k];
    const int q  = b * NN + ii;
    const float nx = xyzp[q*3 + 0];
    const float ny = xyzp[q*3 + 1];
    const float nz = xyzp[q*3 + 2];

    float rx = sx - nx, ry = sy - ny, rz = sz - nz;
    float r2 = rx*rx + ry*ry;
    float rdis = sqrtf(r2 + rz*rz);
    float ralpha = atan2f(ry, rx);
    float rbeta  = atan2f(rz, sqrtf(r2));
    float gdis = __expf(-rdis);

    float mx = redsum16(nx) * 0.0625f;
    float my = redsum16(ny) * 0.0625f;
    float mz = redsum16(nz) * 0.0625f;
    float dx = sx - mx, dy = sy - my, dz = sz - mz;
    float dalpha = atan2f(dy, dx);
    float dbeta  = atan2f(dz, sqrtf(dx*dx + dy*dy));

    // lg_ratio
    float mxd = redmax16(rdis);
    float lv  = mxd * mxd * mxd;
    float nr  = sqrtf(sx*sx + sy*sy + sz*sz);
    float lgr = lv / (nr * nr * nr);

    float rep[9] = { ralpha - dalpha, rbeta - dbeta, rdis, sx, sy, sz, nx, ny, nz };
    float lrep[16];
    #pragma unroll
    for (int o = 0; o < 16; o++){
        float acc = 0.f;
        #pragma unroll
        for (int c = 0; c < 9; c++) acc = fmaf(lm1W[o*9 + c], rep[c], acc);
        lrep[o] = fmaxf(fmaf(lm1g[o], acc, lm1b[o]), 0.f);
    }
    float lrep2[16];
    #pragma unroll
    for (int o = 0; o < 16; o++){
        float acc = 0.f;
        #pragma unroll
        for (int c = 0; c < 16; c++) acc = fmaf(lm2W[o*16 + c], lrep[c], acc);
        lrep2[o] = fmaxf(fmaf(lm2g[o], acc, lm2b[o]), 0.f);
    }

    float fnb[16];
    float sd = 0.f;
    {
        const float4* an = (const float4*)(feat1 + (size_t)q * 16);
        const float4* as = (const float4*)(feat1 + (size_t)p * 16);
        #pragma unroll
        for (int v = 0; v < 4; v++){
            float4 A = an[v]; float4 S = as[v];
            fnb[4*v+0] = A.x; fnb[4*v+1] = A.y; fnb[4*v+2] = A.z; fnb[4*v+3] = A.w;
            sd += fabsf(S.x-A.x) + fabsf(S.y-A.y) + fabsf(S.z-A.z) + fabsf(S.w-A.w);
        }
    }
    float fdis2 = 2.f * __expf(-sd * 0.0625f);

    float lg[32];
    #pragma unroll
    for (int o = 0; o < 32; o++){
        const float* w = p2fc + o*34;
        float acc = w[0] * gdis;
        acc = fmaf(w[1], fdis2, acc);
        #pragma unroll
        for (int c = 0; c < 16; c++) acc = fmaf(w[2 + c],  fnb[c],   acc);
        #pragma unroll
        for (int c = 0; c < 16; c++) acc = fmaf(w[18 + c], lrep2[c], acc);
        lg[o] = acc;
    }
    #pragma unroll
    for (int o = 0; o < 32; o++){
        float m_ = redmax16(lg[o]);
        float e  = __expf(lg[o] - m_);
        float s  = redsum16(e);
        float fsv = (o < 16) ? fnb[o] : lrep2[o - 16];
        float num = redsum16(fsv * e);
        lg[o] = num / s;   // f_mid[o]
    }

    // p2m (relu): lane k computes rows k and k+16
    float actA = 0.f, actB = 0.f;
    #pragma unroll
    for (int c = 0; c < 32; c++){
        actA = fmaf(p2mW[k*32 + c],      lg[c], actA);
        actB = fmaf(p2mW[(k+16)*32 + c], lg[c], actB);
    }
    actA = fmaxf(fmaf(p2mg[k],      actA, p2mb[k]),      0.f);
    actB = fmaxf(fmaf(p2mg[k + 16], actB, p2mb[k + 16]), 0.f);

    // m2 (no act): rows oo = k + 16j via cross-lane broadcast
    float hA[4] = {0.f, 0.f, 0.f, 0.f};
    #pragma unroll
    for (int src = 0; src < 16; src++){
        float a0 = __shfl(actA, src, 16);
        float a1 = __shfl(actB, src, 16);
        #pragma unroll
        for (int j = 0; j < 4; j++){
            hA[j] = fmaf(m2W[(k+16*j)*32 + src],      a0, hA[j]);
            hA[j] = fmaf(m2W[(k+16*j)*32 + src + 16], a1, hA[j]);
        }
    }

    // sc (no act) from original feature; combine with m2 affine
    float xf[16];
    #pragma unroll
    for (int c = 0; c < 16; c++) xf[c] = featp[(b*16 + c)*NN + n];
    #pragma unroll
    for (int j = 0; j < 4; j++){
        int oo = k + 16*j;
        float acc = 0.f;
        #pragma unroll
        for (int c = 0; c < 16; c++) acc = fmaf(scW[oo*16 + c], xf[c], acc);
        float scv = fmaf(scg[oo], acc,   scb[oo]);
        float m2v = fmaf(m2g[oo], hA[j], m2b[oo]);
        hA[j] = m2v + scv;
    }

    // m3 (no act)
    float hG[4];
    #pragma unroll
    for (int j = 0; j < 4; j++){
        int oo = k + 16*j;
        float acc =      m3W[oo*4 + 0] * sx;
        acc = fmaf(m3W[oo*4 + 1], sy,  acc);
        acc = fmaf(m3W[oo*4 + 2], sz,  acc);
        acc = fmaf(m3W[oo*4 + 3], lgr, acc);
        hG[j] = fmaf(m3g[oo], acc, m3b[oo]);
    }

    // stage h[128] per point in LDS
    float (*sH)[132] = (float(*)[132])sPool;
    #pragma unroll
    for (int j = 0; j < 4; j++){
        sH[pt][k + 16*j]      = hA[j];
        sH[pt][64 + k + 16*j] = hG[j];
    }
    __syncthreads();

    // m4 (relu): rows oo = k + 16j; W from global (row broadcast across 16 thr)
    float o4[4] = {0.f, 0.f, 0.f, 0.f};
    #pragma unroll
    for (int cb = 0; cb < 32; cb++){
        const float4 hv = *(const float4*)&sH[pt][cb*4];
        #pragma unroll
        for (int j = 0; j < 4; j++){
            const float4 wv = *(const float4*)&m4W[(k+16*j)*128 + cb*4];
            o4[j] = fmaf(wv.x, hv.x, o4[j]);
            o4[j] = fmaf(wv.y, hv.y, o4[j]);
            o4[j] = fmaf(wv.z, hv.z, o4[j]);
            o4[j] = fmaf(wv.w, hv.w, o4[j]);
        }
    }
    __syncthreads();   // sPool reuse boundary

    float (*sOut)[17] = (float(*)[17])sPool;
    #pragma unroll
    for (int j = 0; j < 4; j++){
        int oo = k + 16*j;
        sOut[oo][pt] = fmaxf(fmaf(m4g[oo], o4[j], m4b[oo]), 0.f);
    }
    __syncthreads();

    // transposed store: thread -> (row oo, 4 consecutive points), float4
    {
        const int oo = threadIdx.x >> 2;
        const int qq = threadIdx.x & 3;
        const int pbase = blockIdx.x << 4;
        const int b0 = pbase / NN;
        const int n0 = pbase - b0 * NN;
        float4 u;
        u.x = sOut[oo][qq*4 + 0];
        u.y = sOut[oo][qq*4 + 1];
        u.z = sOut[oo][qq*4 + 2];
        u.w = sOut[oo][qq*4 + 3];
        *(float4*)(outp + (size_t)(b0*64 + oo)*NN + n0 + qq*4) = u;
    }
}

extern "C" void kernel_launch(void* const* d_in, const int* in_sizes, int n_in,
                              void* d_out, int out_size, void* d_ws, size_t ws_size,
                              hipStream_t stream) {
    float* outp = (float*)d_out;

    // ---- Deterministic diagnostics encoded in a fill value (capture-safe) ----
    // 1.0: assumptions hold (stage2 overwrites everything)
    // 5.0: n_in != 32   7.0: in_sizes mismatch   9.0: out_size mismatch
    // 11.0: ws too small
    float fillv = 1.0f;
    bool ok = true;
    if (n_in != 32) { fillv = 5.0f; ok = false; }
    else if (in_sizes[0] != 1310720 || in_sizes[1] != 245760 ||
             in_sizes[31] != 1310720) { fillv = 7.0f; ok = false; }
    else if (out_size != 5242880) { fillv = 9.0f; ok = false; }
    else if (ws_size < (size_t)2 * NPTS * 16 * sizeof(float)) { fillv = 11.0f; ok = false; }

    k_fill<<<512, 256, 0, stream>>>(outp, fillv, out_size);
    if (!ok) return;

    const float* featp = (const float*)d_in[0];
    const float* xyzp  = (const float*)d_in[1];
    const int*   nidx  = (const int*)d_in[31];

    float* feat0 = (float*)d_ws;                       // NPTS*16 f32 (5.25 MB)
    float* feat1 = (float*)d_ws + (size_t)NPTS * 16;   // NPTS*16 f32 (5.25 MB)

    #define W(i) ((const float*)d_in[2 + (i)])
    k_feat0<<<NPTS/256, 256, 0, stream>>>(featp, W(0), W(1), W(2), feat0);
    k_stage1<<<NPTS/16, 256, 0, stream>>>(xyzp, nidx, feat0,
        W(3), W(4), W(5), W(9), W(10), W(11), W(12), feat1);
    k_stage2<<<NPTS/16, 256, 0, stream>>>(featp, xyzp, nidx, feat1,
        W(3), W(4), W(5),          // lm1
        W(6), W(7), W(8),          // lm2
        W(13),                     // p2fc
        W(14), W(15), W(16),       // p2m
        W(17), W(18), W(19),       // m2
        W(20), W(21), W(22),       // sc
        W(23), W(24), W(25),       // m3
        W(26), W(27), W(28),       // m4
        outp);
    #undef W
}

// Round 6
// 657.817 us; speedup vs baseline: 1.0337x; 1.0337x over previous
//
#include <hip/hip_runtime.h>

#define NN 20480
#define NPTS 81920   // B(4) * N(20480)

__device__ __forceinline__ float redsum16(float v){
    v += __shfl_xor(v, 1); v += __shfl_xor(v, 2);
    v += __shfl_xor(v, 4); v += __shfl_xor(v, 8);
    return v;
}
__device__ __forceinline__ float redmax16(float v){
    v = fmaxf(v, __shfl_xor(v, 1)); v = fmaxf(v, __shfl_xor(v, 2));
    v = fmaxf(v, __shfl_xor(v, 4)); v = fmaxf(v, __shfl_xor(v, 8));
    return v;
}

// Ultra-vanilla fill: diagnostic carrier + deterministic init.
__global__ void k_fill(float* out, float val, int n){
    int i = blockIdx.x * blockDim.x + threadIdx.x;
    int stride = gridDim.x * blockDim.x;
    for (; i < n; i += stride) out[i] = val;
}

// f_pc = relu(g * (m1_W @ feature) + b), stored point-major (B,N,16) f32
__global__ __launch_bounds__(256) void k_feat0(
    const float* __restrict__ featp,
    const float* __restrict__ m1W,
    const float* __restrict__ m1g,
    const float* __restrict__ m1b,
    float* __restrict__ feat0)
{
    int p = blockIdx.x * 256 + threadIdx.x;
    if (p >= NPTS) return;
    int b = p / NN;
    int n = p - b * NN;
    float x[16];
    #pragma unroll
    for (int c = 0; c < 16; c++) x[c] = featp[(b*16 + c)*NN + n];
    float4* dst = (float4*)(feat0 + (size_t)p * 16);
    #pragma unroll
    for (int v = 0; v < 4; v++){
        float4 t; float* tp = (float*)&t;
        #pragma unroll
        for (int u = 0; u < 4; u++){
            int o = 4*v + u;
            float acc = 0.f;
            #pragma unroll
            for (int c = 0; c < 16; c++) acc = fmaf(m1W[o*16 + c], x[c], acc);
            tp[u] = fmaxf(fmaf(m1g[o], acc, m1b[o]), 0.f);
        }
        dst[v] = t;
    }
}

// LDS layouts (floats):
//   sF/sL planes: [pt][k][16], plane stride 260 (=16*16+4), row stride 16
#define PS 260
#define MS 36    // sMid/sAct row stride (16B-aligned rows)

// ---------------- Stage 1 ----------------
// A: geometry+lm1+gather feat0 -> LDS ; B: p1fc+softmax (reg) -> sMid ;
// C: p1m -> feat1
__global__ __launch_bounds__(256) void k_stage1(
    const float* __restrict__ xyzp,
    const int* __restrict__ nidx,
    const float* __restrict__ feat0,
    const float* __restrict__ lm1W,
    const float* __restrict__ lm1g,
    const float* __restrict__ lm1b,
    const float* __restrict__ p1fc,
    const float* __restrict__ p1mW,
    const float* __restrict__ p1mg,
    const float* __restrict__ p1mb,
    float* __restrict__ feat1)
{
    __shared__ float sm[9408];
    // F=0(4160) L=4160(4160) G=8320(256) D=8576(256) MID=8832(576)
    const int k  = threadIdx.x & 15;
    const int pt = threadIdx.x >> 4;
    const int p  = (blockIdx.x << 4) + pt;
    const int b  = p / NN;

    // ---- Phase A ----
    {
        const float sx = xyzp[p*3 + 0];
        const float sy = xyzp[p*3 + 1];
        const float sz = xyzp[p*3 + 2];
        const int ii = nidx[(p << 4) + k];
        const int q  = b * NN + ii;
        const float nx = xyzp[q*3 + 0];
        const float ny = xyzp[q*3 + 1];
        const float nz = xyzp[q*3 + 2];

        float rx = sx - nx, ry = sy - ny, rz = sz - nz;
        float r2 = rx*rx + ry*ry;
        float rdis = sqrtf(r2 + rz*rz);
        float ralpha = atan2f(ry, rx);
        float rbeta  = atan2f(rz, sqrtf(r2));
        float gdis = __expf(-rdis);

        float mx = redsum16(nx) * 0.0625f;
        float my = redsum16(ny) * 0.0625f;
        float mz = redsum16(nz) * 0.0625f;
        float dx = sx - mx, dy = sy - my, dz = sz - mz;
        float dalpha = atan2f(dy, dx);
        float dbeta  = atan2f(dz, sqrtf(dx*dx + dy*dy));

        float rep[9] = { ralpha - dalpha, rbeta - dbeta, rdis, sx, sy, sz, nx, ny, nz };
        float* lRow = sm + 4160 + pt*PS + k*16;
        #pragma unroll
        for (int o = 0; o < 16; o++){
            float acc = 0.f;
            #pragma unroll
            for (int c = 0; c < 9; c++) acc = fmaf(lm1W[o*9 + c], rep[c], acc);
            lRow[o] = fmaxf(fmaf(lm1g[o], acc, lm1b[o]), 0.f);
        }

        float* fRow = sm + pt*PS + k*16;
        float sd = 0.f;
        const float4* an = (const float4*)(feat0 + (size_t)q * 16);
        const float4* as = (const float4*)(feat0 + (size_t)p * 16);
        #pragma unroll
        for (int v = 0; v < 4; v++){
            float4 A = an[v]; float4 S = as[v];
            ((float4*)fRow)[v] = A;
            sd += fabsf(S.x-A.x) + fabsf(S.y-A.y) + fabsf(S.z-A.z) + fabsf(S.w-A.w);
        }
        sm[8320 + pt*16 + k] = gdis;
        sm[8576 + pt*16 + k] = 2.f * __expf(-sd * 0.0625f);   // LAMDA * f_dis
    }
    __syncthreads();

    // ---- Phase B : thread (pt, o2) handles o=o2 and o=o2+16 ----
    {
        const int o2 = k;
        float wA[34], wB[34];
        const float2* a2 = (const float2*)(p1fc + o2*34);
        const float2* b2 = (const float2*)(p1fc + (o2+16)*34);
        #pragma unroll
        for (int i = 0; i < 17; i++){
            float2 t = a2[i]; wA[2*i] = t.x; wA[2*i+1] = t.y;
            float2 u = b2[i]; wB[2*i] = u.x; wB[2*i+1] = u.y;
        }
        const float* fP = sm + pt*PS;
        const float* lP = sm + 4160 + pt*PS;
        float lgA[16], lgB[16];
        float mA = -1e30f, mB = -1e30f;
        #pragma unroll
        for (int kk = 0; kk < 16; kk++){
            float g = sm[8320 + pt*16 + kk];
            float d = sm[8576 + pt*16 + kk];
            float aA = wA[0]*g; aA = fmaf(wA[1], d, aA);
            float aB = wB[0]*g; aB = fmaf(wB[1], d, aB);
            const float* fr = fP + kk*16;
            const float* lr = lP + kk*16;
            #pragma unroll
            for (int v = 0; v < 4; v++){
                float4 F = ((const float4*)fr)[v];
                float4 L = ((const float4*)lr)[v];
                aA = fmaf(wA[2+4*v],  F.x, aA); aA = fmaf(wA[3+4*v],  F.y, aA);
                aA = fmaf(wA[4+4*v],  F.z, aA); aA = fmaf(wA[5+4*v],  F.w, aA);
                aA = fmaf(wA[18+4*v], L.x, aA); aA = fmaf(wA[19+4*v], L.y, aA);
                aA = fmaf(wA[20+4*v], L.z, aA); aA = fmaf(wA[21+4*v], L.w, aA);
                aB = fmaf(wB[2+4*v],  F.x, aB); aB = fmaf(wB[3+4*v],  F.y, aB);
                aB = fmaf(wB[4+4*v],  F.z, aB); aB = fmaf(wB[5+4*v],  F.w, aB);
                aB = fmaf(wB[18+4*v], L.x, aB); aB = fmaf(wB[19+4*v], L.y, aB);
                aB = fmaf(wB[20+4*v], L.z, aB); aB = fmaf(wB[21+4*v], L.w, aB);
            }
            lgA[kk] = aA; lgB[kk] = aB;
            mA = fmaxf(mA, aA); mB = fmaxf(mB, aB);
        }
        float sA = 0.f, nA = 0.f, sB = 0.f, nB = 0.f;
        #pragma unroll
        for (int kk = 0; kk < 16; kk++){
            float eA = __expf(lgA[kk] - mA);
            float eB = __expf(lgB[kk] - mB);
            sA += eA; sB += eB;
            nA = fmaf(eA, fP[kk*16 + o2], nA);
            nB = fmaf(eB, lP[kk*16 + o2], nB);
        }
        sm[8832 + pt*MS + o2]      = nA / sA;
        sm[8832 + pt*MS + o2 + 16] = nB / sB;
    }
    __syncthreads();

    // ---- Phase C : p1m row k ----
    {
        float mid[32];
        const float4* mp = (const float4*)(sm + 8832 + pt*MS);
        #pragma unroll
        for (int i = 0; i < 8; i++){
            float4 t = mp[i];
            mid[4*i]=t.x; mid[4*i+1]=t.y; mid[4*i+2]=t.z; mid[4*i+3]=t.w;
        }
        float acc = 0.f;
        const float4* w4 = (const float4*)(p1mW + k*32);
        #pragma unroll
        for (int i = 0; i < 8; i++){
            float4 w = w4[i];
            acc = fmaf(w.x, mid[4*i],   acc); acc = fmaf(w.y, mid[4*i+1], acc);
            acc = fmaf(w.z, mid[4*i+2], acc); acc = fmaf(w.w, mid[4*i+3], acc);
        }
        feat1[(size_t)(p << 4) + k] = fmaxf(fmaf(p1mg[k], acc, p1mb[k]), 0.f);
    }
}

// ---------------- Stage 2 ----------------
__global__ __launch_bounds__(256) void k_stage2(
    const float* __restrict__ featp,
    const float* __restrict__ xyzp,
    const int* __restrict__ nidx,
    const float* __restrict__ feat1,
    const float* __restrict__ lm1W,
    const float* __restrict__ lm1g,
    const float* __restrict__ lm1b,
    const float* __restrict__ lm2W,
    const float* __restrict__ lm2g,
    const float* __restrict__ lm2b,
    const float* __restrict__ p2fc,
    const float* __restrict__ p2mW,
    const float* __restrict__ p2mg,
    const float* __restrict__ p2mb,
    const float* __restrict__ m2W,
    const float* __restrict__ m2g,
    const float* __restrict__ m2b,
    const float* __restrict__ scW,
    const float* __restrict__ scg,
    const float* __restrict__ scb,
    const float* __restrict__ m3W,
    const float* __restrict__ m3g,
    const float* __restrict__ m3b,
    const float* __restrict__ m4W,
    const float* __restrict__ m4g,
    const float* __restrict__ m4b,
    float* __restrict__ outp)
{
    __shared__ float sm[10000];
    // F=0(4160) L=4160(4160) G=8320(256) D=8576(256) LG=8832(16)
    // MID=8848(576) ACT=9424(576);  sH aliases F (2112), sOut aliases L (1088)
    const int k  = threadIdx.x & 15;
    const int pt = threadIdx.x >> 4;
    const int p  = (blockIdx.x << 4) + pt;
    const int b  = p / NN;
    const int n  = p - b * NN;

    // ---- Phase A ----
    {
        const float sx = xyzp[p*3 + 0];
        const float sy = xyzp[p*3 + 1];
        const float sz = xyzp[p*3 + 2];
        const int ii = nidx[(p << 4) + k];
        const int q  = b * NN + ii;
        const float nx = xyzp[q*3 + 0];
        const float ny = xyzp[q*3 + 1];
        const float nz = xyzp[q*3 + 2];

        float rx = sx - nx, ry = sy - ny, rz = sz - nz;
        float r2 = rx*rx + ry*ry;
        float rdis = sqrtf(r2 + rz*rz);
        float ralpha = atan2f(ry, rx);
        float rbeta  = atan2f(rz, sqrtf(r2));
        float gdis = __expf(-rdis);

        float mx = redsum16(nx) * 0.0625f;
        float my = redsum16(ny) * 0.0625f;
        float mz = redsum16(nz) * 0.0625f;
        float dx = sx - mx, dy = sy - my, dz = sz - mz;
        float dalpha = atan2f(dy, dx);
        float dbeta  = atan2f(dz, sqrtf(dx*dx + dy*dy));

        float mxd = redmax16(rdis);
        float nr  = sqrtf(sx*sx + sy*sy + sz*sz);
        float lgr = (mxd*mxd*mxd) / (nr*nr*nr);
        if (k == 0) sm[8832 + pt] = lgr;

        float rep[9] = { ralpha - dalpha, rbeta - dbeta, rdis, sx, sy, sz, nx, ny, nz };
        float lrep[16];
        #pragma unroll
        for (int o = 0; o < 16; o++){
            float acc = 0.f;
            #pragma unroll
            for (int c = 0; c < 9; c++) acc = fmaf(lm1W[o*9 + c], rep[c], acc);
            lrep[o] = fmaxf(fmaf(lm1g[o], acc, lm1b[o]), 0.f);
        }
        float* lRow = sm + 4160 + pt*PS + k*16;
        #pragma unroll
        for (int o = 0; o < 16; o++){
            float acc = 0.f;
            #pragma unroll
            for (int c = 0; c < 16; c++) acc = fmaf(lm2W[o*16 + c], lrep[c], acc);
            lRow[o] = fmaxf(fmaf(lm2g[o], acc, lm2b[o]), 0.f);   // lrep2
        }

        float* fRow = sm + pt*PS + k*16;
        float sd = 0.f;
        const float4* an = (const float4*)(feat1 + (size_t)q * 16);
        const float4* as = (const float4*)(feat1 + (size_t)p * 16);
        #pragma unroll
        for (int v = 0; v < 4; v++){
            float4 A = an[v]; float4 S = as[v];
            ((float4*)fRow)[v] = A;
            sd += fabsf(S.x-A.x) + fabsf(S.y-A.y) + fabsf(S.z-A.z) + fabsf(S.w-A.w);
        }
        sm[8320 + pt*16 + k] = gdis;
        sm[8576 + pt*16 + k] = 2.f * __expf(-sd * 0.0625f);
    }
    __syncthreads();

    // ---- Phase B : p2fc + softmax, thread (pt,o2) -> f_mid ----
    {
        const int o2 = k;
        float wA[34], wB[34];
        const float2* a2 = (const float2*)(p2fc + o2*34);
        const float2* b2 = (const float2*)(p2fc + (o2+16)*34);
        #pragma unroll
        for (int i = 0; i < 17; i++){
            float2 t = a2[i]; wA[2*i] = t.x; wA[2*i+1] = t.y;
            float2 u = b2[i]; wB[2*i] = u.x; wB[2*i+1] = u.y;
        }
        const float* fP = sm + pt*PS;
        const float* lP = sm + 4160 + pt*PS;
        float lgA[16], lgB[16];
        float mA = -1e30f, mB = -1e30f;
        #pragma unroll
        for (int kk = 0; kk < 16; kk++){
            float g = sm[8320 + pt*16 + kk];
            float d = sm[8576 + pt*16 + kk];
            float aA = wA[0]*g; aA = fmaf(wA[1], d, aA);
            float aB = wB[0]*g; aB = fmaf(wB[1], d, aB);
            const float* fr = fP + kk*16;
            const float* lr = lP + kk*16;
            #pragma unroll
            for (int v = 0; v < 4; v++){
                float4 F = ((const float4*)fr)[v];
                float4 L = ((const float4*)lr)[v];
                aA = fmaf(wA[2+4*v],  F.x, aA); aA = fmaf(wA[3+4*v],  F.y, aA);
                aA = fmaf(wA[4+4*v],  F.z, aA); aA = fmaf(wA[5+4*v],  F.w, aA);
                aA = fmaf(wA[18+4*v], L.x, aA); aA = fmaf(wA[19+4*v], L.y, aA);
                aA = fmaf(wA[20+4*v], L.z, aA); aA = fmaf(wA[21+4*v], L.w, aA);
                aB = fmaf(wB[2+4*v],  F.x, aB); aB = fmaf(wB[3+4*v],  F.y, aB);
                aB = fmaf(wB[4+4*v],  F.z, aB); aB = fmaf(wB[5+4*v],  F.w, aB);
                aB = fmaf(wB[18+4*v], L.x, aB); aB = fmaf(wB[19+4*v], L.y, aB);
                aB = fmaf(wB[20+4*v], L.z, aB); aB = fmaf(wB[21+4*v], L.w, aB);
            }
            lgA[kk] = aA; lgB[kk] = aB;
            mA = fmaxf(mA, aA); mB = fmaxf(mB, aB);
        }
        float sA = 0.f, nA = 0.f, sB = 0.f, nB = 0.f;
        #pragma unroll
        for (int kk = 0; kk < 16; kk++){
            float eA = __expf(lgA[kk] - mA);
            float eB = __expf(lgB[kk] - mB);
            sA += eA; sB += eB;
            nA = fmaf(eA, fP[kk*16 + o2], nA);
            nB = fmaf(eB, lP[kk*16 + o2], nB);
        }
        sm[8848 + pt*MS + o2]      = nA / sA;
        sm[8848 + pt*MS + o2 + 16] = nB / sB;
    }
    __syncthreads();

    // ---- Phase C1 : p2m (relu) -> sAct ----
    {
        float mid[32];
        const float4* mp = (const float4*)(sm + 8848 + pt*MS);
        #pragma unroll
        for (int i = 0; i < 8; i++){
            float4 t = mp[i];
            mid[4*i]=t.x; mid[4*i+1]=t.y; mid[4*i+2]=t.z; mid[4*i+3]=t.w;
        }
        float actA = 0.f, actB = 0.f;
        const float4* wa = (const float4*)(p2mW + k*32);
        const float4* wb = (const float4*)(p2mW + (k+16)*32);
        #pragma unroll
        for (int i = 0; i < 8; i++){
            float4 a = wa[i], c = wb[i];
            actA = fmaf(a.x, mid[4*i], actA);   actA = fmaf(a.y, mid[4*i+1], actA);
            actA = fmaf(a.z, mid[4*i+2], actA); actA = fmaf(a.w, mid[4*i+3], actA);
            actB = fmaf(c.x, mid[4*i], actB);   actB = fmaf(c.y, mid[4*i+1], actB);
            actB = fmaf(c.z, mid[4*i+2], actB); actB = fmaf(c.w, mid[4*i+3], actB);
        }
        sm[9424 + pt*MS + k]      = fmaxf(fmaf(p2mg[k],    actA, p2mb[k]),    0.f);
        sm[9424 + pt*MS + k + 16] = fmaxf(fmaf(p2mg[k+16], actB, p2mb[k+16]), 0.f);
    }
    __syncthreads();

    // ---- Phase C2 : m2 + sc + m3 -> sH ----
    {
        float act[32];
        const float4* ap = (const float4*)(sm + 9424 + pt*MS);
        #pragma unroll
        for (int i = 0; i < 8; i++){
            float4 t = ap[i];
            act[4*i]=t.x; act[4*i+1]=t.y; act[4*i+2]=t.z; act[4*i+3]=t.w;
        }
        float hA[4];
        #pragma unroll
        for (int j = 0; j < 4; j++){
            int oo = k + 16*j;
            float acc = 0.f;
            const float4* w4 = (const float4*)(m2W + oo*32);
            #pragma unroll
            for (int i = 0; i < 8; i++){
                float4 w = w4[i];
                acc = fmaf(w.x, act[4*i],   acc); acc = fmaf(w.y, act[4*i+1], acc);
                acc = fmaf(w.z, act[4*i+2], acc); acc = fmaf(w.w, act[4*i+3], acc);
            }
            hA[j] = acc;
        }
        float xf[16];
        #pragma unroll
        for (int c = 0; c < 16; c++) xf[c] = featp[(b*16 + c)*NN + n];
        #pragma unroll
        for (int j = 0; j < 4; j++){
            int oo = k + 16*j;
            float acc = 0.f;
            const float4* w4 = (const float4*)(scW + oo*16);
            #pragma unroll
            for (int i = 0; i < 4; i++){
                float4 w = w4[i];
                acc = fmaf(w.x, xf[4*i],   acc); acc = fmaf(w.y, xf[4*i+1], acc);
                acc = fmaf(w.z, xf[4*i+2], acc); acc = fmaf(w.w, xf[4*i+3], acc);
            }
            float scv = fmaf(scg[oo], acc,   scb[oo]);
            float m2v = fmaf(m2g[oo], hA[j], m2b[oo]);
            hA[j] = m2v + scv;
        }
        const float sx = xyzp[p*3 + 0];
        const float sy = xyzp[p*3 + 1];
        const float sz = xyzp[p*3 + 2];
        const float lgr = sm[8832 + pt];
        #pragma unroll
        for (int j = 0; j < 4; j++){
            int oo = k + 16*j;
            float acc =      m3W[oo*4 + 0] * sx;
            acc = fmaf(m3W[oo*4 + 1], sy,  acc);
            acc = fmaf(m3W[oo*4 + 2], sz,  acc);
            acc = fmaf(m3W[oo*4 + 3], lgr, acc);
            float hG = fmaf(m3g[oo], acc, m3b[oo]);
            sm[pt*132 + oo]      = hA[j];   // sH aliases F (dead after phase B)
            sm[pt*132 + 64 + oo] = hG;
        }
    }
    __syncthreads();

    // ---- Phase C3 : m4 (relu) ----
    float o4[4] = {0.f, 0.f, 0.f, 0.f};
    {
        const float* hRow = sm + pt*132;
        #pragma unroll
        for (int cb = 0; cb < 32; cb++){
            const float4 hv = *(const float4*)(hRow + cb*4);
            #pragma unroll
            for (int j = 0; j < 4; j++){
                const float4 wv = *(const float4*)&m4W[(k+16*j)*128 + cb*4];
                o4[j] = fmaf(wv.x, hv.x, o4[j]);
                o4[j] = fmaf(wv.y, hv.y, o4[j]);
                o4[j] = fmaf(wv.z, hv.z, o4[j]);
                o4[j] = fmaf(wv.w, hv.w, o4[j]);
            }
        }
    }
    __syncthreads();   // sOut aliases L (dead after phase B)
    #pragma unroll
    for (int j = 0; j < 4; j++){
        int oo = k + 16*j;
        sm[4160 + oo*17 + pt] = fmaxf(fmaf(m4g[oo], o4[j], m4b[oo]), 0.f);
    }
    __syncthreads();
    {
        const int oo = threadIdx.x >> 2;
        const int qq = threadIdx.x & 3;
        const int pbase = blockIdx.x << 4;
        const int b0 = pbase / NN;
        const int n0 = pbase - b0 * NN;
        float4 u;
        u.x = sm[4160 + oo*17 + qq*4 + 0];
        u.y = sm[4160 + oo*17 + qq*4 + 1];
        u.z = sm[4160 + oo*17 + qq*4 + 2];
        u.w = sm[4160 + oo*17 + qq*4 + 3];
        *(float4*)(outp + (size_t)(b0*64 + oo)*NN + n0 + qq*4) = u;
    }
}

extern "C" void kernel_launch(void* const* d_in, const int* in_sizes, int n_in,
                              void* d_out, int out_size, void* d_ws, size_t ws_size,
                              hipStream_t stream) {
    float* outp = (float*)d_out;

    // Deterministic contract check, encoded in fill value (capture-safe).
    float fillv = 1.0f;
    bool ok = true;
    if (n_in != 32) { fillv = 5.0f; ok = false; }
    else if (in_sizes[0] != 1310720 || in_sizes[1] != 245760 ||
             in_sizes[31] != 1310720) { fillv = 7.0f; ok = false; }
    else if (out_size != 5242880) { fillv = 9.0f; ok = false; }
    else if (ws_size < (size_t)2 * NPTS * 16 * sizeof(float)) { fillv = 11.0f; ok = false; }

    k_fill<<<512, 256, 0, stream>>>(outp, fillv, out_size);
    if (!ok) return;

    const float* featp = (const float*)d_in[0];
    const float* xyzp  = (const float*)d_in[1];
    const int*   nidx  = (const int*)d_in[31];

    float* feat0 = (float*)d_ws;                       // NPTS*16 f32
    float* feat1 = (float*)d_ws + (size_t)NPTS * 16;   // NPTS*16 f32

    #define W(i) ((const float*)d_in[2 + (i)])
    k_feat0<<<NPTS/256, 256, 0, stream>>>(featp, W(0), W(1), W(2), feat0);
    k_stage1<<<NPTS/16, 256, 0, stream>>>(xyzp, nidx, feat0,
        W(3), W(4), W(5), W(9), W(10), W(11), W(12), feat1);
    k_stage2<<<NPTS/16, 256, 0, stream>>>(featp, xyzp, nidx, feat1,
        W(3), W(4), W(5),          // lm1
        W(6), W(7), W(8),          // lm2
        W(13),                     // p2fc
        W(14), W(15), W(16),       // p2m
        W(17), W(18), W(19),       // m2
        W(20), W(21), W(22),       // sc
        W(23), W(24), W(25),       // m3
        W(26), W(27), W(28),       // m4
        outp);
    #undef W
}

// Round 7
// 639.322 us; speedup vs baseline: 1.0636x; 1.0289x over previous
//
#include <hip/hip_runtime.h>

#define NN 20480
#define NPTS 81920   // B(4) * N(20480)
#define PS 260       // per-point plane stride (16k x 16ch + 4 pad)
#define MS 36        // mid/act row stride

__device__ __forceinline__ float redsum16(float v){
    v += __shfl_xor(v, 1); v += __shfl_xor(v, 2);
    v += __shfl_xor(v, 4); v += __shfl_xor(v, 8);
    return v;
}
__device__ __forceinline__ float redmax16(float v){
    v = fmaxf(v, __shfl_xor(v, 1)); v = fmaxf(v, __shfl_xor(v, 2));
    v = fmaxf(v, __shfl_xor(v, 4)); v = fmaxf(v, __shfl_xor(v, 8));
    return v;
}
// Wave-scope LDS producer->consumer fence. All phase dataflow is wave-local:
// DS ops complete in-order per wave; wave_barrier pins compiler ordering,
// threadfence_block provides the waitcnt.
__device__ __forceinline__ void wsync(){
    __builtin_amdgcn_wave_barrier();
    __threadfence_block();
    __builtin_amdgcn_wave_barrier();
}

__global__ void k_fill4(float4* out, float val, int n4){
    int i = blockIdx.x * blockDim.x + threadIdx.x;
    int stride = gridDim.x * blockDim.x;
    float4 v = make_float4(val, val, val, val);
    for (; i < n4; i += stride) out[i] = v;
}

// f_pc = relu(g * (m1_W @ feature) + b), stored point-major (B,N,16) f32
__global__ __launch_bounds__(256) void k_feat0(
    const float* __restrict__ featp,
    const float* __restrict__ m1W,
    const float* __restrict__ m1g,
    const float* __restrict__ m1b,
    float* __restrict__ feat0)
{
    int p = blockIdx.x * 256 + threadIdx.x;
    if (p >= NPTS) return;
    int b = p / NN;
    int n = p - b * NN;
    float x[16];
    #pragma unroll
    for (int c = 0; c < 16; c++) x[c] = featp[(b*16 + c)*NN + n];
    float4* dst = (float4*)(feat0 + (size_t)p * 16);
    #pragma unroll
    for (int v = 0; v < 4; v++){
        float4 t; float* tp = (float*)&t;
        #pragma unroll
        for (int u = 0; u < 4; u++){
            int o = 4*v + u;
            float acc = 0.f;
            #pragma unroll
            for (int c = 0; c < 16; c++) acc = fmaf(m1W[o*16 + c], x[c], acc);
            tp[u] = fmaxf(fmaf(m1g[o], acc, m1b[o]), 0.f);
        }
        dst[v] = t;
    }
}

// ---------------- Stage 1 ----------------
// block=128 (2 waves, 8 points, 16 lanes/point); all phases wave-local.
// LDS floats: F=0(2080) L=2080(2080) G=4160(128) D=4288(128) MID=4416(288)
__global__ __launch_bounds__(128) void k_stage1(
    const float* __restrict__ xyzp,
    const int* __restrict__ nidx,
    const float* __restrict__ feat0,
    const float* __restrict__ lm1W,
    const float* __restrict__ lm1g,
    const float* __restrict__ lm1b,
    const float* __restrict__ p1fc,
    const float* __restrict__ p1mW,
    const float* __restrict__ p1mg,
    const float* __restrict__ p1mb,
    float* __restrict__ feat1)
{
    __shared__ float sm[4704];
    const int k  = threadIdx.x & 15;
    const int pt = threadIdx.x >> 4;          // 0..7
    const int p  = (blockIdx.x << 3) + pt;
    const int b  = p / NN;

    // ---- Phase A ----
    {
        const int ii = nidx[(p << 4) + k];
        const int q  = b * NN + ii;
        const float4* an = (const float4*)(feat0 + (size_t)q * 16);
        const float4* as = (const float4*)(feat0 + (size_t)p * 16);
        const float sx = xyzp[p*3 + 0];
        const float sy = xyzp[p*3 + 1];
        const float sz = xyzp[p*3 + 2];
        const float nx = xyzp[q*3 + 0];
        const float ny = xyzp[q*3 + 1];
        const float nz = xyzp[q*3 + 2];

        float* fRow = sm + pt*PS + k*16;
        float sd = 0.f;
        #pragma unroll
        for (int v = 0; v < 4; v++){
            float4 A = an[v]; float4 S = as[v];
            ((float4*)fRow)[v] = A;
            sd += fabsf(S.x-A.x) + fabsf(S.y-A.y) + fabsf(S.z-A.z) + fabsf(S.w-A.w);
        }
        sm[4288 + pt*16 + k] = 2.f * __expf(-sd * 0.0625f);   // LAMDA * f_dis

        float rx = sx - nx, ry = sy - ny, rz = sz - nz;
        float r2 = rx*rx + ry*ry;
        float rdis = sqrtf(r2 + rz*rz);
        float ralpha = atan2f(ry, rx);
        float rbeta  = atan2f(rz, sqrtf(r2));
        sm[4160 + pt*16 + k] = __expf(-rdis);                 // g_dis

        float mx = redsum16(nx) * 0.0625f;
        float my = redsum16(ny) * 0.0625f;
        float mz = redsum16(nz) * 0.0625f;
        float dx = sx - mx, dy = sy - my, dz = sz - mz;
        float dalpha = atan2f(dy, dx);
        float dbeta  = atan2f(dz, sqrtf(dx*dx + dy*dy));

        float rep[9] = { ralpha - dalpha, rbeta - dbeta, rdis, sx, sy, sz, nx, ny, nz };
        float* lRow = sm + 2080 + pt*PS + k*16;
        #pragma unroll
        for (int o = 0; o < 16; o++){
            float acc = 0.f;
            #pragma unroll
            for (int c = 0; c < 9; c++) acc = fmaf(lm1W[o*9 + c], rep[c], acc);
            lRow[o] = fmaxf(fmaf(lm1g[o], acc, lm1b[o]), 0.f);
        }
    }
    wsync();

    // ---- Phase B : lane (pt,o2) handles channels o2 and o2+16 ----
    {
        const int o2 = k;
        float wA[34], wB[34];
        const float2* a2 = (const float2*)(p1fc + o2*34);
        const float2* b2 = (const float2*)(p1fc + (o2+16)*34);
        #pragma unroll
        for (int i = 0; i < 17; i++){
            float2 t = a2[i]; wA[2*i] = t.x; wA[2*i+1] = t.y;
            float2 u = b2[i]; wB[2*i] = u.x; wB[2*i+1] = u.y;
        }
        const float* fP = sm + pt*PS;
        const float* lP = sm + 2080 + pt*PS;
        float lgA[16], lgB[16];
        float mA = -1e30f, mB = -1e30f;
        #pragma unroll
        for (int kk = 0; kk < 16; kk++){
            float g = sm[4160 + pt*16 + kk];
            float d = sm[4288 + pt*16 + kk];
            float aA = wA[0]*g; aA = fmaf(wA[1], d, aA);
            float aB = wB[0]*g; aB = fmaf(wB[1], d, aB);
            const float* fr = fP + kk*16;
            const float* lr = lP + kk*16;
            #pragma unroll
            for (int v = 0; v < 4; v++){
                float4 F = ((const float4*)fr)[v];
                float4 L = ((const float4*)lr)[v];
                aA = fmaf(wA[2+4*v],  F.x, aA); aA = fmaf(wA[3+4*v],  F.y, aA);
                aA = fmaf(wA[4+4*v],  F.z, aA); aA = fmaf(wA[5+4*v],  F.w, aA);
                aA = fmaf(wA[18+4*v], L.x, aA); aA = fmaf(wA[19+4*v], L.y, aA);
                aA = fmaf(wA[20+4*v], L.z, aA); aA = fmaf(wA[21+4*v], L.w, aA);
                aB = fmaf(wB[2+4*v],  F.x, aB); aB = fmaf(wB[3+4*v],  F.y, aB);
                aB = fmaf(wB[4+4*v],  F.z, aB); aB = fmaf(wB[5+4*v],  F.w, aB);
                aB = fmaf(wB[18+4*v], L.x, aB); aB = fmaf(wB[19+4*v], L.y, aB);
                aB = fmaf(wB[20+4*v], L.z, aB); aB = fmaf(wB[21+4*v], L.w, aB);
            }
            lgA[kk] = aA; lgB[kk] = aB;
            mA = fmaxf(mA, aA); mB = fmaxf(mB, aB);
        }
        float sA = 0.f, nA = 0.f, sB = 0.f, nB = 0.f;
        #pragma unroll
        for (int kk = 0; kk < 16; kk++){
            float eA = __expf(lgA[kk] - mA);
            float eB = __expf(lgB[kk] - mB);
            sA += eA; sB += eB;
            nA = fmaf(eA, fP[kk*16 + o2], nA);
            nB = fmaf(eB, lP[kk*16 + o2], nB);
        }
        sm[4416 + pt*MS + o2]      = nA / sA;
        sm[4416 + pt*MS + o2 + 16] = nB / sB;
    }
    wsync();

    // ---- Phase C : p1m row k ----
    {
        float mid[32];
        const float4* mp = (const float4*)(sm + 4416 + pt*MS);
        #pragma unroll
        for (int i = 0; i < 8; i++){
            float4 t = mp[i];
            mid[4*i]=t.x; mid[4*i+1]=t.y; mid[4*i+2]=t.z; mid[4*i+3]=t.w;
        }
        float acc = 0.f;
        const float4* w4 = (const float4*)(p1mW + k*32);
        #pragma unroll
        for (int i = 0; i < 8; i++){
            float4 w = w4[i];
            acc = fmaf(w.x, mid[4*i],   acc); acc = fmaf(w.y, mid[4*i+1], acc);
            acc = fmaf(w.z, mid[4*i+2], acc); acc = fmaf(w.w, mid[4*i+3], acc);
        }
        feat1[(size_t)(p << 4) + k] = fmaxf(fmaf(p1mg[k], acc, p1mb[k]), 0.f);
    }
}

// ---------------- Stage 2 ----------------
// LDS floats: F=0(2080) L=2080(2080) G=4160(128) D=4288(128) LGR=4416(8)
//             MID=4424(288) ACT=4712(288)
// sH aliases each pt's F slice (132 of 260); sOut aliases wave's L half.
__global__ __launch_bounds__(128) void k_stage2(
    const float* __restrict__ featp,
    const float* __restrict__ xyzp,
    const int* __restrict__ nidx,
    const float* __restrict__ feat1,
    const float* __restrict__ lm1W,
    const float* __restrict__ lm1g,
    const float* __restrict__ lm1b,
    const float* __restrict__ lm2W,
    const float* __restrict__ lm2g,
    const float* __restrict__ lm2b,
    const float* __restrict__ p2fc,
    const float* __restrict__ p2mW,
    const float* __restrict__ p2mg,
    const float* __restrict__ p2mb,
    const float* __restrict__ m2W,
    const float* __restrict__ m2g,
    const float* __restrict__ m2b,
    const float* __restrict__ scW,
    const float* __restrict__ scg,
    const float* __restrict__ scb,
    const float* __restrict__ m3W,
    const float* __restrict__ m3g,
    const float* __restrict__ m3b,
    const float* __restrict__ m4W,
    const float* __restrict__ m4g,
    const float* __restrict__ m4b,
    float* __restrict__ outp)
{
    __shared__ float sm[5000];
    const int k  = threadIdx.x & 15;
    const int pt = threadIdx.x >> 4;          // 0..7
    const int p  = (blockIdx.x << 3) + pt;
    const int b  = p / NN;
    const int n  = p - b * NN;

    // ---- Phase A ----
    {
        const int ii = nidx[(p << 4) + k];
        const int q  = b * NN + ii;
        const float4* an = (const float4*)(feat1 + (size_t)q * 16);
        const float4* as = (const float4*)(feat1 + (size_t)p * 16);
        const float sx = xyzp[p*3 + 0];
        const float sy = xyzp[p*3 + 1];
        const float sz = xyzp[p*3 + 2];
        const float nx = xyzp[q*3 + 0];
        const float ny = xyzp[q*3 + 1];
        const float nz = xyzp[q*3 + 2];

        float* fRow = sm + pt*PS + k*16;
        float sd = 0.f;
        #pragma unroll
        for (int v = 0; v < 4; v++){
            float4 A = an[v]; float4 S = as[v];
            ((float4*)fRow)[v] = A;
            sd += fabsf(S.x-A.x) + fabsf(S.y-A.y) + fabsf(S.z-A.z) + fabsf(S.w-A.w);
        }
        sm[4288 + pt*16 + k] = 2.f * __expf(-sd * 0.0625f);

        float rx = sx - nx, ry = sy - ny, rz = sz - nz;
        float r2 = rx*rx + ry*ry;
        float rdis = sqrtf(r2 + rz*rz);
        float ralpha = atan2f(ry, rx);
        float rbeta  = atan2f(rz, sqrtf(r2));
        sm[4160 + pt*16 + k] = __expf(-rdis);

        float mx = redsum16(nx) * 0.0625f;
        float my = redsum16(ny) * 0.0625f;
        float mz = redsum16(nz) * 0.0625f;
        float dx = sx - mx, dy = sy - my, dz = sz - mz;
        float dalpha = atan2f(dy, dx);
        float dbeta  = atan2f(dz, sqrtf(dx*dx + dy*dy));

        float mxd = redmax16(rdis);
        float nr  = sqrtf(sx*sx + sy*sy + sz*sz);
        if (k == 0) sm[4416 + pt] = (mxd*mxd*mxd) / (nr*nr*nr);   // lg_ratio

        float rep[9] = { ralpha - dalpha, rbeta - dbeta, rdis, sx, sy, sz, nx, ny, nz };
        float lrep[16];
        #pragma unroll
        for (int o = 0; o < 16; o++){
            float acc = 0.f;
            #pragma unroll
            for (int c = 0; c < 9; c++) acc = fmaf(lm1W[o*9 + c], rep[c], acc);
            lrep[o] = fmaxf(fmaf(lm1g[o], acc, lm1b[o]), 0.f);
        }
        float* lRow = sm + 2080 + pt*PS + k*16;
        #pragma unroll
        for (int o = 0; o < 16; o++){
            float acc = 0.f;
            #pragma unroll
            for (int c = 0; c < 16; c++) acc = fmaf(lm2W[o*16 + c], lrep[c], acc);
            lRow[o] = fmaxf(fmaf(lm2g[o], acc, lm2b[o]), 0.f);   // lrep2
        }
    }
    wsync();

    // ---- Phase B : p2fc + softmax -> MID ----
    {
        const int o2 = k;
        float wA[34], wB[34];
        const float2* a2 = (const float2*)(p2fc + o2*34);
        const float2* b2 = (const float2*)(p2fc + (o2+16)*34);
        #pragma unroll
        for (int i = 0; i < 17; i++){
            float2 t = a2[i]; wA[2*i] = t.x; wA[2*i+1] = t.y;
            float2 u = b2[i]; wB[2*i] = u.x; wB[2*i+1] = u.y;
        }
        const float* fP = sm + pt*PS;
        const float* lP = sm + 2080 + pt*PS;
        float lgA[16], lgB[16];
        float mA = -1e30f, mB = -1e30f;
        #pragma unroll
        for (int kk = 0; kk < 16; kk++){
            float g = sm[4160 + pt*16 + kk];
            float d = sm[4288 + pt*16 + kk];
            float aA = wA[0]*g; aA = fmaf(wA[1], d, aA);
            float aB = wB[0]*g; aB = fmaf(wB[1], d, aB);
            const float* fr = fP + kk*16;
            const float* lr = lP + kk*16;
            #pragma unroll
            for (int v = 0; v < 4; v++){
                float4 F = ((const float4*)fr)[v];
                float4 L = ((const float4*)lr)[v];
                aA = fmaf(wA[2+4*v],  F.x, aA); aA = fmaf(wA[3+4*v],  F.y, aA);
                aA = fmaf(wA[4+4*v],  F.z, aA); aA = fmaf(wA[5+4*v],  F.w, aA);
                aA = fmaf(wA[18+4*v], L.x, aA); aA = fmaf(wA[19+4*v], L.y, aA);
                aA = fmaf(wA[20+4*v], L.z, aA); aA = fmaf(wA[21+4*v], L.w, aA);
                aB = fmaf(wB[2+4*v],  F.x, aB); aB = fmaf(wB[3+4*v],  F.y, aB);
                aB = fmaf(wB[4+4*v],  F.z, aB); aB = fmaf(wB[5+4*v],  F.w, aB);
                aB = fmaf(wB[18+4*v], L.x, aB); aB = fmaf(wB[19+4*v], L.y, aB);
                aB = fmaf(wB[20+4*v], L.z, aB); aB = fmaf(wB[21+4*v], L.w, aB);
            }
            lgA[kk] = aA; lgB[kk] = aB;
            mA = fmaxf(mA, aA); mB = fmaxf(mB, aB);
        }
        float sA = 0.f, nA = 0.f, sB = 0.f, nB = 0.f;
        #pragma unroll
        for (int kk = 0; kk < 16; kk++){
            float eA = __expf(lgA[kk] - mA);
            float eB = __expf(lgB[kk] - mB);
            sA += eA; sB += eB;
            nA = fmaf(eA, fP[kk*16 + o2], nA);
            nB = fmaf(eB, lP[kk*16 + o2], nB);
        }
        sm[4424 + pt*MS + o2]      = nA / sA;
        sm[4424 + pt*MS + o2 + 16] = nB / sB;
    }
    wsync();

    // ---- Phase C1 : p2m (relu) -> ACT ----
    {
        float mid[32];
        const float4* mp = (const float4*)(sm + 4424 + pt*MS);
        #pragma unroll
        for (int i = 0; i < 8; i++){
            float4 t = mp[i];
            mid[4*i]=t.x; mid[4*i+1]=t.y; mid[4*i+2]=t.z; mid[4*i+3]=t.w;
        }
        float actA = 0.f, actB = 0.f;
        const float4* wa = (const float4*)(p2mW + k*32);
        const float4* wb = (const float4*)(p2mW + (k+16)*32);
        #pragma unroll
        for (int i = 0; i < 8; i++){
            float4 a = wa[i], c = wb[i];
            actA = fmaf(a.x, mid[4*i], actA);   actA = fmaf(a.y, mid[4*i+1], actA);
            actA = fmaf(a.z, mid[4*i+2], actA); actA = fmaf(a.w, mid[4*i+3], actA);
            actB = fmaf(c.x, mid[4*i], actB);   actB = fmaf(c.y, mid[4*i+1], actB);
            actB = fmaf(c.z, mid[4*i+2], actB); actB = fmaf(c.w, mid[4*i+3], actB);
        }
        sm[4712 + pt*MS + k]      = fmaxf(fmaf(p2mg[k],    actA, p2mb[k]),    0.f);
        sm[4712 + pt*MS + k + 16] = fmaxf(fmaf(p2mg[k+16], actB, p2mb[k+16]), 0.f);
    }
    wsync();

    // ---- Phase C2 : m2 + sc + m3 -> sH (aliases pt's F slice) ----
    {
        float act[32];
        const float4* ap = (const float4*)(sm + 4712 + pt*MS);
        #pragma unroll
        for (int i = 0; i < 8; i++){
            float4 t = ap[i];
            act[4*i]=t.x; act[4*i+1]=t.y; act[4*i+2]=t.z; act[4*i+3]=t.w;
        }
        float hA[4];
        #pragma unroll
        for (int j = 0; j < 4; j++){
            int oo = k + 16*j;
            float acc = 0.f;
            const float4* w4 = (const float4*)(m2W + oo*32);
            #pragma unroll
            for (int i = 0; i < 8; i++){
                float4 w = w4[i];
                acc = fmaf(w.x, act[4*i],   acc); acc = fmaf(w.y, act[4*i+1], acc);
                acc = fmaf(w.z, act[4*i+2], acc); acc = fmaf(w.w, act[4*i+3], acc);
            }
            hA[j] = acc;
        }
        float xf[16];
        #pragma unroll
        for (int c = 0; c < 16; c++) xf[c] = featp[(b*16 + c)*NN + n];
        #pragma unroll
        for (int j = 0; j < 4; j++){
            int oo = k + 16*j;
            float acc = 0.f;
            const float4* w4 = (const float4*)(scW + oo*16);
            #pragma unroll
            for (int i = 0; i < 4; i++){
                float4 w = w4[i];
                acc = fmaf(w.x, xf[4*i],   acc); acc = fmaf(w.y, xf[4*i+1], acc);
                acc = fmaf(w.z, xf[4*i+2], acc); acc = fmaf(w.w, xf[4*i+3], acc);
            }
            float scv = fmaf(scg[oo], acc,   scb[oo]);
            float m2v = fmaf(m2g[oo], hA[j], m2b[oo]);
            hA[j] = m2v + scv;
        }
        const float sx = xyzp[p*3 + 0];
        const float sy = xyzp[p*3 + 1];
        const float sz = xyzp[p*3 + 2];
        const float lgr = sm[4416 + pt];
        float* sH = sm + pt*PS;     // F slice of this pt (dead after phase B)
        #pragma unroll
        for (int j = 0; j < 4; j++){
            int oo = k + 16*j;
            float acc =      m3W[oo*4 + 0] * sx;
            acc = fmaf(m3W[oo*4 + 1], sy,  acc);
            acc = fmaf(m3W[oo*4 + 2], sz,  acc);
            acc = fmaf(m3W[oo*4 + 3], lgr, acc);
            sH[oo]      = hA[j];
            sH[64 + oo] = fmaf(m3g[oo], acc, m3b[oo]);
        }
    }
    wsync();

    // ---- Phase C3 : m4 (relu) + wave-local transpose + store ----
    float o4[4] = {0.f, 0.f, 0.f, 0.f};
    {
        const float* hRow = sm + pt*PS;
        #pragma unroll
        for (int cb = 0; cb < 32; cb++){
            const float4 hv = *(const float4*)(hRow + cb*4);
            #pragma unroll
            for (int j = 0; j < 4; j++){
                const float4 wv = *(const float4*)&m4W[(k+16*j)*128 + cb*4];
                o4[j] = fmaf(wv.x, hv.x, o4[j]);
                o4[j] = fmaf(wv.y, hv.y, o4[j]);
                o4[j] = fmaf(wv.z, hv.z, o4[j]);
                o4[j] = fmaf(wv.w, hv.w, o4[j]);
            }
        }
    }
    wsync();   // sOut aliases wave's L half (dead after phase B)
    {
        const int w   = threadIdx.x >> 6;     // wave id (0/1)
        const int l   = threadIdx.x & 63;
        float* sOutW  = sm + 2080 + w*1040;   // 256 floats used
        const int pt3 = pt & 3;
        #pragma unroll
        for (int j = 0; j < 4; j++)
            sOutW[4*(k + 16*j) + pt3] = fmaxf(fmaf(m4g[k+16*j], o4[j], m4b[k+16*j]), 0.f);
        wsync();
        const int pbase = blockIdx.x << 3;
        const int b0 = pbase / NN;
        const int n0 = pbase - b0 * NN + 4*w;
        float4 u = *(const float4*)(sOutW + 4*l);
        *(float4*)(outp + (size_t)(b0*64 + l)*NN + n0) = u;
    }
}

extern "C" void kernel_launch(void* const* d_in, const int* in_sizes, int n_in,
                              void* d_out, int out_size, void* d_ws, size_t ws_size,
                              hipStream_t stream) {
    float* outp = (float*)d_out;

    // Deterministic contract check, encoded in fill value (capture-safe).
    float fillv = 1.0f;
    bool ok = true;
    if (n_in != 32) { fillv = 5.0f; ok = false; }
    else if (in_sizes[0] != 1310720 || in_sizes[1] != 245760 ||
             in_sizes[31] != 1310720) { fillv = 7.0f; ok = false; }
    else if (out_size != 5242880) { fillv = 9.0f; ok = false; }
    else if (ws_size < (size_t)2 * NPTS * 16 * sizeof(float)) { fillv = 11.0f; ok = false; }

    k_fill4<<<1024, 256, 0, stream>>>((float4*)outp, fillv, out_size/4);
    if (!ok) return;

    const float* featp = (const float*)d_in[0];
    const float* xyzp  = (const float*)d_in[1];
    const int*   nidx  = (const int*)d_in[31];

    float* feat0 = (float*)d_ws;                       // NPTS*16 f32
    float* feat1 = (float*)d_ws + (size_t)NPTS * 16;   // NPTS*16 f32

    #define W(i) ((const float*)d_in[2 + (i)])
    k_feat0<<<NPTS/256, 256, 0, stream>>>(featp, W(0), W(1), W(2), feat0);
    k_stage1<<<NPTS/8, 128, 0, stream>>>(xyzp, nidx, feat0,
        W(3), W(4), W(5), W(9), W(10), W(11), W(12), feat1);
    k_stage2<<<NPTS/8, 128, 0, stream>>>(featp, xyzp, nidx, feat1,
        W(3), W(4), W(5),          // lm1
        W(6), W(7), W(8),          // lm2
        W(13),                     // p2fc
        W(14), W(15), W(16),       // p2m
        W(17), W(18), W(19),       // m2
        W(20), W(21), W(22),       // sc
        W(23), W(24), W(25),       // m3
        W(26), W(27), W(28),       // m4
        outp);
    #undef W
}